// Round 18
// baseline (213.571 us; speedup 1.0000x reference)
//
#include <hip/hip_runtime.h>
#include <hip/hip_bf16.h>

#define B_ 32
#define S_ 1024
#define D_ 512
#define H_ 8
#define DH_ 64
#define QBLK 64
#define KVB 64
#define NBLK 4096
#define NEGF (-1e30f)
#define THR 8.0f

using f32x4 = __attribute__((ext_vector_type(4))) float;
using bf16x8 = __attribute__((ext_vector_type(8))) short;
using bf16x4 = __attribute__((ext_vector_type(4))) short;

__device__ __forceinline__ unsigned int cvt_pk_bf16(float lo, float hi) {
  unsigned int r;
  asm("v_cvt_pk_bf16_f32 %0, %1, %2" : "=v"(r) : "v"(lo), "v"(hi));
  return r;
}

__device__ __forceinline__ f32x4 mfma16(bf16x8 a, bf16x8 b, f32x4 c) {
  return __builtin_amdgcn_mfma_f32_16x16x32_bf16(a, b, c, 0, 0, 0);
}

// K tile [kv=64][dh=64] (128B rows): XOR col bits 3..5 with (row^row>>3).
__device__ __forceinline__ int swz(int r) { return ((r ^ (r >> 3)) & 7) << 3; }
// V tile [dh=64][kv=64] (128B rows): XOR col bits 2..5 (4 bits — 64-wide kv).
// Write banks: slot = (kvE/2)^(sw/2) with kvE/2 = tid&31 spanning all 32
// banks -> conflict-free (was 4-way at KVB=32). Reads stay 4-clk optimal.
__device__ __forceinline__ int swzV(int r) { return ((r ^ (r >> 3)) & 15) << 2; }

// r18 = r17 softmax/fragment structure at KVB=64: halves tile count ->
// halves barrier/lgkm/issue/loop fixed costs per unit work. Staging regs
// 24->49 transient (peak live ~125 < (256,3)=170 proven budget, r7 held 144).
// LDS 48KB -> 3 blocks/CU = 12 waves cap ~= the 11 currently achieved.
__global__ __launch_bounds__(256, 3) void attn_kernel(
    const float* __restrict__ qg, const float* __restrict__ kg,
    const float* __restrict__ v1g, const float* __restrict__ v2g,
    const int* __restrict__ cmask, float* __restrict__ out) {
  // XCD-bijective swizzle (4096 % 8 == 0): contiguous chunk per XCD
  const int wg = ((int)blockIdx.x & 7) * (NBLK / 8) + ((int)blockIdx.x >> 3);
  const int qb = 15 - (wg & 15);  // heavy (large-qb) blocks dispatch first
  const int h = (wg >> 4) & 7;
  const int b = wg >> 7;
  const int qt = qb * QBLK;
  const int tid = threadIdx.x;
  const int wid = tid >> 6;        // wave owns q rows qt+wid*16 .. +15
  const int lane = tid & 63;
  const int l15 = lane & 15;
  const int lg = lane >> 4;

  __shared__ alignas(16) unsigned short sK[2][KVB * 64];   // [kv][dh^swz(kv)]
  __shared__ alignas(16) unsigned short sV1[2][64 * KVB];  // [dh][kv^swzV(dh)]
  __shared__ alignas(16) unsigned short sV2[2][64 * KVB];
  __shared__ unsigned int sMaskW[32];  // counter mask bits, u32 word t = keys 32t..+31

  const float SCL = 0.125f * 1.44269504089f;  // 1/sqrt(DH) * log2(e), folded into Q
  const int qrow = qt + wid * 16 + l15;       // this lane's q-row (softmax axis)

  // wave-uniform bases + 32-bit per-lane offsets
  const float* qgb = qg + (size_t)b * S_ * D_ + h * DH_;
  const float* kgb = kg + (size_t)b * S_ * D_ + h * DH_;
  const float* v1b = v1g + (size_t)b * S_ * D_ + h * DH_;
  const float* v2b = v2g + (size_t)b * S_ * D_ + h * DH_;
  const int cmb = b * S_;

  // ---- counter-mask words, built ONCE (tile ti uses words 2ti, 2ti+1)
#pragma unroll
  for (int c = 0; c < 4; ++c) {
    const int chunk = wid * 4 + c;  // 0..15, keys chunk*64..+63
    const int cm = cmask[cmb + chunk * 64 + lane];
    const unsigned long long bm = __ballot(cm != 0);
    if (lane == 0) {
      sMaskW[2 * chunk] = (unsigned int)bm;
      sMaskW[2 * chunk + 1] = (unsigned int)(bm >> 32);
    }
  }

  // Q fragments (B operand): col=l15 -> qrow, k = jk*32 + lg*8 + i
  bf16x8 qf[2];
  {
    const float* qp = qgb + (unsigned)qrow * D_;
#pragma unroll
    for (int jk = 0; jk < 2; ++jk) {
      float4 a = *reinterpret_cast<const float4*>(qp + jk * 32 + lg * 8);
      float4 c = *reinterpret_cast<const float4*>(qp + jk * 32 + lg * 8 + 4);
      bf16x8 q8;
      reinterpret_cast<unsigned int*>(&q8)[0] = cvt_pk_bf16(a.x * SCL, a.y * SCL);
      reinterpret_cast<unsigned int*>(&q8)[1] = cvt_pk_bf16(a.z * SCL, a.w * SCL);
      reinterpret_cast<unsigned int*>(&q8)[2] = cvt_pk_bf16(c.x * SCL, c.y * SCL);
      reinterpret_cast<unsigned int*>(&q8)[3] = cvt_pk_bf16(c.z * SCL, c.w * SCL);
      qf[jk] = q8;
    }
  }

  // --- staging partitions (KVB=64) ---
  // K: thread -> (row skv 0..63, 16 cols sd0..+15), two b128 LDS writes
  const int skv = tid >> 2;
  const int sd0 = (tid & 3) * 16;
  const int sKoff0 = skv * 64 + (sd0 ^ swz(skv));
  const int sKoff1 = skv * 64 + ((sd0 + 8) ^ swz(skv));
  const unsigned int oK = (unsigned)skv * D_ + sd0;
  // V: thread -> (kv pair kvE,kvE+1 of 64, d cols dsel..+3 and dsel+32..+35)
  const int kvE = (tid >> 3) * 2;
  const int dsel = (tid & 7) * 4;
  const unsigned int oV = (unsigned)kvE * D_ + dsel;

  // cross-tile prefetch for t+1 (49 regs, transient through stage_write)
  float4 rK0, rK1, rK2, rK3;
  float4 rV1a0, rV1a1, rV1b0, rV1b1;  // V1 rows kvE,kvE+1 x col-blocks {dsel, dsel+32}
  float4 rV2a0, rV2a1, rV2b0, rV2b1;
  int rCm = 1;
  auto issue = [&](int kv0) {
    const float* p = kgb + (oK + (unsigned)kv0 * D_);
    rK0 = *reinterpret_cast<const float4*>(p);
    rK1 = *reinterpret_cast<const float4*>(p + 4);
    rK2 = *reinterpret_cast<const float4*>(p + 8);
    rK3 = *reinterpret_cast<const float4*>(p + 12);
    const float* pv1 = v1b + (oV + (unsigned)kv0 * D_);
    const float* pv2 = v2b + (oV + (unsigned)kv0 * D_);
    rV1a0 = *reinterpret_cast<const float4*>(pv1);
    rV1a1 = *reinterpret_cast<const float4*>(pv1 + 32);
    rV1b0 = *reinterpret_cast<const float4*>(pv1 + D_);
    rV1b1 = *reinterpret_cast<const float4*>(pv1 + D_ + 32);
    rV2a0 = *reinterpret_cast<const float4*>(pv2);
    rV2a1 = *reinterpret_cast<const float4*>(pv2 + 32);
    rV2b0 = *reinterpret_cast<const float4*>(pv2 + D_);
    rV2b1 = *reinterpret_cast<const float4*>(pv2 + D_ + 32);
    if (tid < KVB) rCm = cmask[cmb + kv0 + tid];
  };

  auto stage_write = [&](int buf) {
    bf16x8 kw;
    reinterpret_cast<unsigned int*>(&kw)[0] = cvt_pk_bf16(rK0.x, rK0.y);
    reinterpret_cast<unsigned int*>(&kw)[1] = cvt_pk_bf16(rK0.z, rK0.w);
    reinterpret_cast<unsigned int*>(&kw)[2] = cvt_pk_bf16(rK1.x, rK1.y);
    reinterpret_cast<unsigned int*>(&kw)[3] = cvt_pk_bf16(rK1.z, rK1.w);
    *reinterpret_cast<bf16x8*>(&sK[buf][sKoff0]) = kw;
    reinterpret_cast<unsigned int*>(&kw)[0] = cvt_pk_bf16(rK2.x, rK2.y);
    reinterpret_cast<unsigned int*>(&kw)[1] = cvt_pk_bf16(rK2.z, rK2.w);
    reinterpret_cast<unsigned int*>(&kw)[2] = cvt_pk_bf16(rK3.x, rK3.y);
    reinterpret_cast<unsigned int*>(&kw)[3] = cvt_pk_bf16(rK3.z, rK3.w);
    *reinterpret_cast<bf16x8*>(&sK[buf][sKoff1]) = kw;

    float va1[8], vb1[8], va2[8], vb2[8];  // [0..3]=cols dsel.., [4..7]=dsel+32..
    *reinterpret_cast<float4*>(&va1[0]) = rV1a0;
    *reinterpret_cast<float4*>(&va1[4]) = rV1a1;
    *reinterpret_cast<float4*>(&vb1[0]) = rV1b0;
    *reinterpret_cast<float4*>(&vb1[4]) = rV1b1;
    *reinterpret_cast<float4*>(&va2[0]) = rV2a0;
    *reinterpret_cast<float4*>(&va2[4]) = rV2a1;
    *reinterpret_cast<float4*>(&vb2[0]) = rV2b0;
    *reinterpret_cast<float4*>(&vb2[4]) = rV2b1;
#pragma unroll
    for (int e = 0; e < 8; ++e) {
      const int d = dsel + (e & 3) + ((e >> 2) * 32);
      const int off = d * KVB + (kvE ^ swzV(d));  // kvE even; swzV has no bit0/1
      *reinterpret_cast<unsigned int*>(&sV1[buf][off]) = cvt_pk_bf16(va1[e], vb1[e]);
      *reinterpret_cast<unsigned int*>(&sV2[buf][off]) = cvt_pk_bf16(va2[e], vb2[e]);
    }
  };

  f32x4 o1[4], o2[4];
  float m_ = NEGF, l_ = 0.f;  // l_ is a per-lane PARTIAL (16 keys); reduced at end
#pragma unroll
  for (int i = 0; i < 4; ++i) {
    o1[i] = f32x4{0.f, 0.f, 0.f, 0.f};
    o2[i] = f32x4{0.f, 0.f, 0.f, 0.f};
  }

  const int ntile = qb + 1;  // strictly-causal tiles of 64 keys
  issue(0);
  for (int ti = 0; ti < ntile; ++ti) {
    const int kv0 = ti * KVB;
    const int buf = ti & 1;
    stage_write(buf);                       // implicit vmcnt wait on own loads
    if (ti + 1 < ntile) issue(kv0 + KVB);   // in flight across barrier + compute
    asm volatile("s_waitcnt lgkmcnt(0)" ::: "memory");
    __builtin_amdgcn_s_barrier();           // single barrier/tile (dbuf => WAR safe)
    __builtin_amdgcn_sched_barrier(0);

    if (kv0 <= qt + wid * 16 + 14) {  // wave-level causal skip (wave-uniform)
      // ---- S^T = K.Q^T : lane holds S[kv0 + nb*16 + lg*4 + r][qrow]
      f32x4 sa[4];
      __builtin_amdgcn_s_setprio(1);  // T5
#pragma unroll
      for (int nb = 0; nb < 4; ++nb) {
        sa[nb] = f32x4{0.f, 0.f, 0.f, 0.f};
        const int key = nb * 16 + l15;
#pragma unroll
        for (int jk = 0; jk < 2; ++jk) {
          bf16x8 kf = *reinterpret_cast<const bf16x8*>(
              &sK[buf][key * 64 + ((jk * 32 + lg * 8) ^ swz(key))]);
          sa[nb] = mfma16(kf, qf[jk], sa[nb]);
        }
      }
      __builtin_amdgcn_s_setprio(0);
      // ---- in-lane mask (two u32 halves) + per-lane max
      const unsigned int mlo = sMaskW[2 * ti];
      const unsigned int mhi = sMaskW[2 * ti + 1];
      int thr = qrow - kv0;
      thr = thr < 0 ? 0 : (thr > 64 ? 64 : thr);
      const unsigned int alo =
          mlo & ((thr >= 32) ? 0xFFFFFFFFu : ((1u << thr) - 1u));
      const int th = thr - 32;
      const unsigned int ahi =
          mhi & ((th >= 32) ? 0xFFFFFFFFu
                            : (th <= 0 ? 0u : ((1u << th) - 1u)));
      float pmax = NEGF;
#pragma unroll
      for (int nb = 0; nb < 4; ++nb) {
        const unsigned int word = (nb < 2) ? alo : ahi;
        const unsigned int sub = (word >> ((nb & 1) * 16 + lg * 4)) & 0xFu;
#pragma unroll
        for (int r = 0; r < 4; ++r) {
          const float s = (sub & (1u << r)) ? sa[nb][r] : NEGF;
          sa[nb][r] = s;
          pmax = fmaxf(pmax, s);
        }
      }
      // ---- T13 defer-max: rescale only when some row grew its max by >THR
      if (__any(pmax > m_ + THR)) {
        float mx = fmaxf(pmax, __shfl_xor(pmax, 16));
        mx = fmaxf(mx, __shfl_xor(mx, 32));
        const float mnew = fmaxf(m_, mx);
        const float fac = exp2f(m_ - mnew);
        l_ *= fac;
        m_ = mnew;
#pragma unroll
        for (int nd = 0; nd < 4; ++nd) { o1[nd] *= fac; o2[nd] *= fac; }
      }
      float rs = 0.f;
#pragma unroll
      for (int nb = 0; nb < 4; ++nb)
#pragma unroll
        for (int r = 0; r < 4; ++r) {
          const float p = exp2f(sa[nb][r] - m_);
          sa[nb][r] = p;
          rs += p;
        }
      l_ += rs;                  // per-lane partial; reduced at end

      // ---- P packed in registers; pb[jk] slot i carries
      // key = 32jk + 16*(i>>2) + lg*4 + (i&3) == sa[2jk+(i>>2)][i&3] (r7-proven)
      bf16x8 pb[2];
#pragma unroll
      for (int jk = 0; jk < 2; ++jk) {
        reinterpret_cast<unsigned int*>(&pb[jk])[0] =
            cvt_pk_bf16(sa[2 * jk][0], sa[2 * jk][1]);
        reinterpret_cast<unsigned int*>(&pb[jk])[1] =
            cvt_pk_bf16(sa[2 * jk][2], sa[2 * jk][3]);
        reinterpret_cast<unsigned int*>(&pb[jk])[2] =
            cvt_pk_bf16(sa[2 * jk + 1][0], sa[2 * jk + 1][1]);
        reinterpret_cast<unsigned int*>(&pb[jk])[3] =
            cvt_pk_bf16(sa[2 * jk + 1][2], sa[2 * jk + 1][3]);
      }

      // ---- PV: A-frag (V^T) read in the SAME key order
      __builtin_amdgcn_s_setprio(1);  // T5
#pragma unroll
      for (int nd = 0; nd < 4; ++nd) {
        const int drow = nd * 16 + l15;
        const int swd = swzV(drow);
        const int rbase = drow * KVB;       // stride 64
#pragma unroll
        for (int jk = 0; jk < 2; ++jk) {
          const int kvA = (32 * jk + lg * 4) ^ swd;
          const int kvB = (32 * jk + 16 + lg * 4) ^ swd;
          bf16x8 v1f, v2f;
          *reinterpret_cast<bf16x4*>(&v1f) =
              *reinterpret_cast<const bf16x4*>(&sV1[buf][rbase + kvA]);
          *reinterpret_cast<bf16x4*>(reinterpret_cast<short*>(&v1f) + 4) =
              *reinterpret_cast<const bf16x4*>(&sV1[buf][rbase + kvB]);
          *reinterpret_cast<bf16x4*>(&v2f) =
              *reinterpret_cast<const bf16x4*>(&sV2[buf][rbase + kvA]);
          *reinterpret_cast<bf16x4*>(reinterpret_cast<short*>(&v2f) + 4) =
              *reinterpret_cast<const bf16x4*>(&sV2[buf][rbase + kvB]);
          o1[nd] = mfma16(v1f, pb[jk], o1[nd]);
          o2[nd] = mfma16(v2f, pb[jk], o2[nd]);
        }
      }
      __builtin_amdgcn_s_setprio(0);
    }
  }

  // ---- finish l: reduce the per-lane partials across the row's 4 lanes
  float lsum = l_;
  lsum += __shfl_xor(lsum, 16);
  lsum += __shfl_xor(lsum, 32);

  // ---- degenerate rows (no allowed keys): uniform softmax = mean of V over S.
  const bool deg = (m_ <= -9.9e29f);
  float* cb = reinterpret_cast<float*>(&sK[0][0]);  // sK dead; reuse (4096 f32)
  const int blockDeg = __syncthreads_or(deg ? 1 : 0);
  if (blockDeg) {
    const int d = tid & 63;
    const int sg = tid >> 6;  // 0..3
    float c1 = 0.f, c2 = 0.f;
    const float* p1 = v1b + d;
    const float* p2 = v2b + d;
#pragma unroll 4
    for (int s = sg; s < S_; s += 4) {
      c1 += p1[(unsigned)s * D_];
      c2 += p2[(unsigned)s * D_];
    }
    cb[sg * 64 + d] = c1;
    cb[256 + sg * 64 + d] = c2;
    __syncthreads();
    if (tid < 64) {
      float t1 = 0.f, t2 = 0.f;
#pragma unroll
      for (int g = 0; g < 4; ++g) { t1 += cb[g * 64 + tid]; t2 += cb[256 + g * 64 + tid]; }
      cb[512 + tid] = t1;
      cb[576 + tid] = t2;
    }
    __syncthreads();
  }

  // ---- epilogue: O^T layout -> d-contiguous float4 stores
  float* outB = out + (size_t)B_ * S_ * D_;
  const float invl = deg ? (1.0f / (float)S_) : (1.0f / lsum);
  const size_t rbase = ((size_t)b * S_ + qrow) * D_ + h * DH_;
#pragma unroll
  for (int nd = 0; nd < 4; ++nd) {
    const int d0 = nd * 16 + lg * 4;
    float4 cs1 = {0.f, 0.f, 0.f, 0.f}, cs2 = {0.f, 0.f, 0.f, 0.f};
    if (blockDeg) {
      cs1 = *reinterpret_cast<const float4*>(&cb[512 + d0]);
      cs2 = *reinterpret_cast<const float4*>(&cb[576 + d0]);
    }
    float4 w1, w2;
    w1.x = (deg ? cs1.x : o1[nd][0]) * invl;
    w1.y = (deg ? cs1.y : o1[nd][1]) * invl;
    w1.z = (deg ? cs1.z : o1[nd][2]) * invl;
    w1.w = (deg ? cs1.w : o1[nd][3]) * invl;
    w2.x = (deg ? cs2.x : o2[nd][0]) * invl;
    w2.y = (deg ? cs2.y : o2[nd][1]) * invl;
    w2.z = (deg ? cs2.z : o2[nd][2]) * invl;
    w2.w = (deg ? cs2.w : o2[nd][3]) * invl;
    *reinterpret_cast<float4*>(&out[rbase + d0]) = w1;
    *reinterpret_cast<float4*>(&outB[rbase + d0]) = w2;
  }
}

extern "C" void kernel_launch(void* const* d_in, const int* in_sizes, int n_in,
                              void* d_out, int out_size, void* d_ws, size_t ws_size,
                              hipStream_t stream) {
  const float* q = (const float*)d_in[0];
  const float* k = (const float*)d_in[1];
  const float* v1 = (const float*)d_in[2];
  const float* v2 = (const float*)d_in[3];
  const int* cm = (const int*)d_in[4];
  float* out = (float*)d_out;

  attn_kernel<<<dim3(NBLK), dim3(256), 0, stream>>>(q, k, v1, v2, cm, out);
}

// Round 19
// 172.743 us; speedup vs baseline: 1.2364x; 1.2364x over previous
//
#include <hip/hip_runtime.h>
#include <hip/hip_bf16.h>

#define B_ 32
#define S_ 1024
#define D_ 512
#define H_ 8
#define DH_ 64
#define QBLK 64
#define KVB 32
#define NWAVE 4
#define NBLK 4096
#define NEGF (-1e30f)
#define THR 8.0f

using f32x4 = __attribute__((ext_vector_type(4))) float;
using bf16x8 = __attribute__((ext_vector_type(8))) short;
using bf16x4 = __attribute__((ext_vector_type(4))) short;

__device__ __forceinline__ unsigned int cvt_pk_bf16(float lo, float hi) {
  unsigned int r;
  asm("v_cvt_pk_bf16_f32 %0, %1, %2" : "=v"(r) : "v"(lo), "v"(hi));
  return r;
}

__device__ __forceinline__ f32x4 mfma16(bf16x8 a, bf16x8 b, f32x4 c) {
  return __builtin_amdgcn_mfma_f32_16x16x32_bf16(a, b, c, 0, 0, 0);
}

// K tile [kv=32][dh=64]: XOR bits 3..5 of the column with (row ^ row>>3).
__device__ __forceinline__ int swz(int r) { return ((r ^ (r >> 3)) & 7) << 3; }
// V tile [dh=64][kv=32] (stride 32): XOR bits 2..4 of the column.
__device__ __forceinline__ int swzV(int r) { return ((r ^ (r >> 3)) & 7) << 2; }

// FINAL (r17, 173us): r14 optimum + T5 s_setprio around the MFMA clusters.
// Structural enlargements all rejected by the ~112-reg combined budget:
// r15 qb-pairing (L3 thrash), r16 QBLK=128 (spill), r18 KVB=64 (spill).
__global__ __launch_bounds__(256, 3) void attn_kernel(
    const float* __restrict__ qg, const float* __restrict__ kg,
    const float* __restrict__ v1g, const float* __restrict__ v2g,
    const int* __restrict__ cmask, float* __restrict__ out) {
  // XCD-bijective swizzle (4096 % 8 == 0): contiguous chunk per XCD
  const int wg = ((int)blockIdx.x & 7) * (NBLK / 8) + ((int)blockIdx.x >> 3);
  const int qb = 15 - (wg & 15);  // heavy (large-qb) blocks dispatch first
  const int h = (wg >> 4) & 7;
  const int b = wg >> 7;
  const int qt = qb * QBLK;
  const int tid = threadIdx.x;
  const int wid = tid >> 6;        // wave owns q rows qt+wid*16 .. +15
  const int lane = tid & 63;
  const int l15 = lane & 15;
  const int lg = lane >> 4;

  __shared__ alignas(16) unsigned short sK[2][KVB * 64];   // [kv][dh^swz(kv)]
  __shared__ alignas(16) unsigned short sV1[2][64 * KVB];  // [dh][kv^swzV(dh)]
  __shared__ alignas(16) unsigned short sV2[2][64 * KVB];
  __shared__ unsigned int sMaskW[32];  // counter mask bits, word t = keys 32t..+31

  const float SCL = 0.125f * 1.44269504089f;  // 1/sqrt(DH) * log2(e), folded into Q
  const int qrow = qt + wid * 16 + l15;       // this lane's q-row (softmax axis)

  // wave-uniform bases + 32-bit per-lane offsets
  const float* qgb = qg + (size_t)b * S_ * D_ + h * DH_;
  const float* kgb = kg + (size_t)b * S_ * D_ + h * DH_;
  const float* v1b = v1g + (size_t)b * S_ * D_ + h * DH_;
  const float* v2b = v2g + (size_t)b * S_ * D_ + h * DH_;
  const int cmb = b * S_;

  // ---- counter-mask words, built ONCE
#pragma unroll
  for (int c = 0; c < 4; ++c) {
    const int chunk = wid * 4 + c;  // 0..15, keys chunk*64..+63
    const int cm = cmask[cmb + chunk * 64 + lane];
    const unsigned long long bm = __ballot(cm != 0);
    if (lane == 0) {
      sMaskW[2 * chunk] = (unsigned int)bm;
      sMaskW[2 * chunk + 1] = (unsigned int)(bm >> 32);
    }
  }

  // Q fragments (B operand): col=l15 -> qrow, k = jk*32 + lg*8 + i
  bf16x8 qf[2];
  {
    const float* qp = qgb + (unsigned)qrow * D_;
#pragma unroll
    for (int jk = 0; jk < 2; ++jk) {
      float4 a = *reinterpret_cast<const float4*>(qp + jk * 32 + lg * 8);
      float4 c = *reinterpret_cast<const float4*>(qp + jk * 32 + lg * 8 + 4);
      bf16x8 q8;
      reinterpret_cast<unsigned int*>(&q8)[0] = cvt_pk_bf16(a.x * SCL, a.y * SCL);
      reinterpret_cast<unsigned int*>(&q8)[1] = cvt_pk_bf16(a.z * SCL, a.w * SCL);
      reinterpret_cast<unsigned int*>(&q8)[2] = cvt_pk_bf16(c.x * SCL, c.y * SCL);
      reinterpret_cast<unsigned int*>(&q8)[3] = cvt_pk_bf16(c.z * SCL, c.w * SCL);
      qf[jk] = q8;
    }
  }

  // --- staging partitions ---
  // K: thread -> (row skv 0..31, 8 cols sd0..+7), one b128 LDS write
  const int skv = tid >> 3;
  const int sd0 = (tid & 7) * 8;
  const int sKoff = skv * 64 + (sd0 ^ swz(skv));
  const unsigned int oK = (unsigned)skv * D_ + sd0;
  // V: thread -> (kv pair kvE,kvE+1 of 32, dh quad dq..+3), 4 b32 writes per V
  const int kvE = (tid >> 4) * 2;
  const int dq = (tid & 15) * 4;
  const unsigned int oV = (unsigned)kvE * D_ + dq;

  // cross-tile prefetch for t+1 (24 regs), proven r7/r11 shape
  float4 rK0, rK1, rV1a, rV1b, rV2a, rV2b;
  auto issue = [&](int kv0) {
    const float* p = kgb + (oK + (unsigned)kv0 * D_);
    rK0 = *reinterpret_cast<const float4*>(p);
    rK1 = *reinterpret_cast<const float4*>(p + 4);
    const float* pv1 = v1b + (oV + (unsigned)kv0 * D_);
    const float* pv2 = v2b + (oV + (unsigned)kv0 * D_);
    rV1a = *reinterpret_cast<const float4*>(pv1);
    rV1b = *reinterpret_cast<const float4*>(pv1 + D_);
    rV2a = *reinterpret_cast<const float4*>(pv2);
    rV2b = *reinterpret_cast<const float4*>(pv2 + D_);
  };

  auto stage_write = [&](int buf) {
    bf16x8 kw;
    reinterpret_cast<unsigned int*>(&kw)[0] = cvt_pk_bf16(rK0.x, rK0.y);
    reinterpret_cast<unsigned int*>(&kw)[1] = cvt_pk_bf16(rK0.z, rK0.w);
    reinterpret_cast<unsigned int*>(&kw)[2] = cvt_pk_bf16(rK1.x, rK1.y);
    reinterpret_cast<unsigned int*>(&kw)[3] = cvt_pk_bf16(rK1.z, rK1.w);
    *reinterpret_cast<bf16x8*>(&sK[buf][sKoff]) = kw;
    const float* a1 = reinterpret_cast<const float*>(&rV1a);
    const float* b1 = reinterpret_cast<const float*>(&rV1b);
    const float* a2 = reinterpret_cast<const float*>(&rV2a);
    const float* b2 = reinterpret_cast<const float*>(&rV2b);
#pragma unroll
    for (int e = 0; e < 4; ++e) {
      const int d = dq + e;
      const int off = d * KVB + (kvE ^ swzV(d));  // stride 32; swzV has no bit0/1
      *reinterpret_cast<unsigned int*>(&sV1[buf][off]) = cvt_pk_bf16(a1[e], b1[e]);
      *reinterpret_cast<unsigned int*>(&sV2[buf][off]) = cvt_pk_bf16(a2[e], b2[e]);
    }
  };

  f32x4 o1[4], o2[4];
  float m_ = NEGF, l_ = 0.f;  // l_ is a per-lane PARTIAL (8 keys); reduced at end
#pragma unroll
  for (int i = 0; i < 4; ++i) {
    o1[i] = f32x4{0.f, 0.f, 0.f, 0.f};
    o2[i] = f32x4{0.f, 0.f, 0.f, 0.f};
  }

  const int ntile = 2 * qb + 2;  // strictly-causal tiles of 32 keys
  issue(0);
  for (int ti = 0; ti < ntile; ++ti) {
    const int kv0 = ti * KVB;
    const int buf = ti & 1;
    stage_write(buf);                       // implicit vmcnt wait on own loads
    if (ti + 1 < ntile) issue(kv0 + KVB);   // in flight across barrier + compute
    asm volatile("s_waitcnt lgkmcnt(0)" ::: "memory");
    __builtin_amdgcn_s_barrier();           // single barrier/tile (dbuf => WAR safe)
    __builtin_amdgcn_sched_barrier(0);

    if (kv0 <= qt + wid * 16 + 14) {  // wave-level causal skip (wave-uniform)
      // ---- S^T = K.Q^T : lane holds S[kv0 + nb*16 + lg*4 + r][qrow]
      f32x4 sa[2];
      __builtin_amdgcn_s_setprio(1);  // T5: keep matrix pipe fed vs co-resident
#pragma unroll
      for (int nb = 0; nb < 2; ++nb) {
        sa[nb] = f32x4{0.f, 0.f, 0.f, 0.f};
        const int key = nb * 16 + l15;
#pragma unroll
        for (int jk = 0; jk < 2; ++jk) {
          bf16x8 kf = *reinterpret_cast<const bf16x8*>(
              &sK[buf][key * 64 + ((jk * 32 + lg * 8) ^ swz(key))]);
          sa[nb] = mfma16(kf, qf[jk], sa[nb]);
        }
      }
      __builtin_amdgcn_s_setprio(0);
      // ---- in-lane mask + per-lane max
      const unsigned int bits = sMaskW[ti];
      int thr = qrow - kv0;
      thr = thr < 0 ? 0 : (thr > KVB ? KVB : thr);
      const unsigned int allow =
          bits & ((thr >= 32) ? 0xFFFFFFFFu : ((1u << thr) - 1u));
      float pmax = NEGF;
#pragma unroll
      for (int nb = 0; nb < 2; ++nb) {
        const unsigned int sub = (allow >> (nb * 16 + lg * 4)) & 0xFu;
#pragma unroll
        for (int r = 0; r < 4; ++r) {
          const float s = (sub & (1u << r)) ? sa[nb][r] : NEGF;
          sa[nb][r] = s;
          pmax = fmaxf(pmax, s);
        }
      }
      // ---- T13 defer-max: rescale only when some row grew its max by >THR.
      if (__any(pmax > m_ + THR)) {
        float mx = fmaxf(pmax, __shfl_xor(pmax, 16));
        mx = fmaxf(mx, __shfl_xor(mx, 32));
        const float mnew = fmaxf(m_, mx);
        const float fac = exp2f(m_ - mnew);
        l_ *= fac;
        m_ = mnew;
#pragma unroll
        for (int nd = 0; nd < 4; ++nd) { o1[nd] *= fac; o2[nd] *= fac; }
      }
      float rs = 0.f;
#pragma unroll
      for (int nb = 0; nb < 2; ++nb)
#pragma unroll
        for (int r = 0; r < 4; ++r) {
          const float p = exp2f(sa[nb][r] - m_);
          sa[nb][r] = p;
          rs += p;
        }
      l_ += rs;                  // per-lane partial; reduced at end

      // ---- P packed in registers; B-frag slot i carries
      // key = (i>>2)*16 + lg*4 + (i&3) == sa[i>>2][i&3] (K=32: one MFMA step)
      bf16x8 pb;
      reinterpret_cast<unsigned int*>(&pb)[0] = cvt_pk_bf16(sa[0][0], sa[0][1]);
      reinterpret_cast<unsigned int*>(&pb)[1] = cvt_pk_bf16(sa[0][2], sa[0][3]);
      reinterpret_cast<unsigned int*>(&pb)[2] = cvt_pk_bf16(sa[1][0], sa[1][1]);
      reinterpret_cast<unsigned int*>(&pb)[3] = cvt_pk_bf16(sa[1][2], sa[1][3]);

      // ---- PV: A-frag (V^T) read in the SAME key order, one MFMA per (nd,V)
      __builtin_amdgcn_s_setprio(1);  // T5
#pragma unroll
      for (int nd = 0; nd < 4; ++nd) {
        const int drow = nd * 16 + l15;
        const int swd = swzV(drow);
        const int rbase = drow * KVB;       // stride 32
        const int kvA = (lg * 4) ^ swd;
        const int kvB = (16 + lg * 4) ^ swd;
        bf16x8 v1f, v2f;
        *reinterpret_cast<bf16x4*>(&v1f) =
            *reinterpret_cast<const bf16x4*>(&sV1[buf][rbase + kvA]);
        *reinterpret_cast<bf16x4*>(reinterpret_cast<short*>(&v1f) + 4) =
            *reinterpret_cast<const bf16x4*>(&sV1[buf][rbase + kvB]);
        *reinterpret_cast<bf16x4*>(&v2f) =
            *reinterpret_cast<const bf16x4*>(&sV2[buf][rbase + kvA]);
        *reinterpret_cast<bf16x4*>(reinterpret_cast<short*>(&v2f) + 4) =
            *reinterpret_cast<const bf16x4*>(&sV2[buf][rbase + kvB]);
        o1[nd] = mfma16(v1f, pb, o1[nd]);
        o2[nd] = mfma16(v2f, pb, o2[nd]);
      }
      __builtin_amdgcn_s_setprio(0);
    }
  }

  // ---- finish l: reduce the per-lane partials across the row's 4 lanes
  float lsum = l_;
  lsum += __shfl_xor(lsum, 16);
  lsum += __shfl_xor(lsum, 32);

  // ---- degenerate rows (no allowed keys): uniform softmax = mean of V over S.
  const bool deg = (m_ <= -9.9e29f);
  float* cb = reinterpret_cast<float*>(&sK[0][0]);  // sK dead; reuse (2048 f32)
  const int blockDeg = __syncthreads_or(deg ? 1 : 0);
  if (blockDeg) {
    const int d = tid & 63;
    const int sg = tid >> 6;  // 0..3
    float c1 = 0.f, c2 = 0.f;
    const float* p1 = v1b + d;
    const float* p2 = v2b + d;
#pragma unroll 4
    for (int s = sg; s < S_; s += 4) {
      c1 += p1[(unsigned)s * D_];
      c2 += p2[(unsigned)s * D_];
    }
    cb[sg * 64 + d] = c1;
    cb[256 + sg * 64 + d] = c2;
    __syncthreads();
    if (tid < 64) {
      float t1 = 0.f, t2 = 0.f;
#pragma unroll
      for (int g = 0; g < 4; ++g) { t1 += cb[g * 64 + tid]; t2 += cb[256 + g * 64 + tid]; }
      cb[512 + tid] = t1;
      cb[576 + tid] = t2;
    }
    __syncthreads();
  }

  // ---- epilogue: O^T layout -> d-contiguous float4 stores
  float* outB = out + (size_t)B_ * S_ * D_;
  const float invl = deg ? (1.0f / (float)S_) : (1.0f / lsum);
  const size_t rbase = ((size_t)b * S_ + qrow) * D_ + h * DH_;
#pragma unroll
  for (int nd = 0; nd < 4; ++nd) {
    const int d0 = nd * 16 + lg * 4;
    float4 cs1 = {0.f, 0.f, 0.f, 0.f}, cs2 = {0.f, 0.f, 0.f, 0.f};
    if (blockDeg) {
      cs1 = *reinterpret_cast<const float4*>(&cb[512 + d0]);
      cs2 = *reinterpret_cast<const float4*>(&cb[576 + d0]);
    }
    float4 w1, w2;
    w1.x = (deg ? cs1.x : o1[nd][0]) * invl;
    w1.y = (deg ? cs1.y : o1[nd][1]) * invl;
    w1.z = (deg ? cs1.z : o1[nd][2]) * invl;
    w1.w = (deg ? cs1.w : o1[nd][3]) * invl;
    w2.x = (deg ? cs2.x : o2[nd][0]) * invl;
    w2.y = (deg ? cs2.y : o2[nd][1]) * invl;
    w2.z = (deg ? cs2.z : o2[nd][2]) * invl;
    w2.w = (deg ? cs2.w : o2[nd][3]) * invl;
    *reinterpret_cast<float4*>(&out[rbase + d0]) = w1;
    *reinterpret_cast<float4*>(&outB[rbase + d0]) = w2;
  }
}

extern "C" void kernel_launch(void* const* d_in, const int* in_sizes, int n_in,
                              void* d_out, int out_size, void* d_ws, size_t ws_size,
                              hipStream_t stream) {
  const float* q = (const float*)d_in[0];
  const float* k = (const float*)d_in[1];
  const float* v1 = (const float*)d_in[2];
  const float* v2 = (const float*)d_in[3];
  const int* cm = (const int*)d_in[4];
  float* out = (float*)d_out;

  attn_kernel<<<dim3(NBLK), dim3(256), 0, stream>>>(q, k, v1, v2, cm, out);
}